// Round 10
// baseline (194.211 us; speedup 1.0000x reference)
//
#include <hip/hip_runtime.h>
#include <stdint.h>

#define N_EMBD 1024
#define NHEAD  16
#define HDIM   64
#define BATCH  8
#define SEQ    1024
#define MROWS  (BATCH*SEQ)   // 8192

typedef __bf16 bf16x8 __attribute__((ext_vector_type(8)));
typedef float  f32x4  __attribute__((ext_vector_type(4)));

__device__ inline unsigned short f2bf(float f) {
  uint32_t u = __float_as_uint(f);
  u += 0x7FFFu + ((u >> 16) & 1u);   // RNE; inputs are finite
  return (unsigned short)(u >> 16);
}

__device__ inline f32x4 mfma_bf16(bf16x8 a, bf16x8 b, f32x4 c) {
  return __builtin_amdgcn_mfma_f32_16x16x32_bf16(a, b, c, 0, 0, 0);
}

__device__ inline void gload_lds16(const unsigned short* g, unsigned short* l) {
  __builtin_amdgcn_global_load_lds(
      (const __attribute__((address_space(1))) void*)g,
      (__attribute__((address_space(3))) void*)l,
      16, 0, 0);
}

// ---------------- transpose + cast: in [K][N] f32 -> out [N][K] bf16 ----------------
__global__ __launch_bounds__(256) void transpose_cast(
    const float* __restrict__ in, unsigned short* __restrict__ out, int K, int N) {
  __shared__ unsigned short tile[64 * 72];
  int k0 = blockIdx.y * 64, n0 = blockIdx.x * 64;
  int t = threadIdx.x;
  {
    int col = (t & 15) * 4;
#pragma unroll
    for (int it = 0; it < 4; ++it) {
      int row = (t >> 4) + it * 16;
      float4 v = *(const float4*)(in + (size_t)(k0 + row) * N + n0 + col);
      ushort4 o;
      o.x = f2bf(v.x); o.y = f2bf(v.y); o.z = f2bf(v.z); o.w = f2bf(v.w);
      *(ushort4*)&tile[row * 72 + col] = o;
    }
  }
  __syncthreads();
  {
    int kcol = (t & 7) * 8;
#pragma unroll
    for (int it = 0; it < 2; ++it) {
      int nrow = (t >> 3) + it * 32;
      alignas(16) unsigned short tmp[8];
#pragma unroll
      for (int j = 0; j < 8; ++j) tmp[j] = tile[(kcol + j) * 72 + nrow];
      *(uint4*)(out + (size_t)(n0 + nrow) * K + k0 + kcol) = *(const uint4*)tmp;
    }
  }
}

// ---------------- GEMM v7: m97 structure + zero-conflict swizzle + cache-shaped grid ----
// 128x128 tile, BK=64, 4 waves (2x2), per-wave 64x64 = acc[4][4]. Single 32KB LDS buffer,
// plain __syncthreads() loop (m114 cross-block overlap). LDS rows 128B, col XOR-swizzle
// realized via pre-swizzled source + linear dest (rule #21); reads use the same XOR.
// Grid decode (in-kernel): each XCD owns 8 contiguous m-bands; n walked in chunks of 8
// so the active B-slice (2MB) + A band stay L2-resident per XCD.

// Shared compute body; expects m0, n0 already computed. Defines wr,wc,g,fr,acc for epilogue.
#define GEMM97_BODY(ATYPE_STAGE)                                                \
  __shared__ unsigned short Asl[128 * 64];                                      \
  __shared__ unsigned short Bsl[128 * 64];                                      \
  const int tid = threadIdx.x;                                                  \
  const int l = tid & 63, w = tid >> 6;                                         \
  const int wr = w >> 1, wc = w & 1;                                            \
  const int g = l >> 4, fr = l & 15;                                            \
  f32x4 acc[4][4];                                                              \
  _Pragma("unroll") for (int i = 0; i < 4; ++i)                                 \
    _Pragma("unroll") for (int j = 0; j < 4; ++j)                               \
      _Pragma("unroll") for (int r = 0; r < 4; ++r) acc[i][j][r] = 0.0f;        \
  const int rr = tid >> 3;                                                      \
  const int cs = ((tid & 7) * 16) ^ ((rr & 7) << 4);                            \
  const int ldso = tid * 8; /* shorts; byte tid*16 */                           \
  const int arow = (wr * 64 + fr) * 128;                                        \
  const int brow = (wc * 64 + fr) * 128;                                        \
  int colk[2];                                                                  \
  colk[0] = (g * 16) ^ ((fr & 7) << 4);                                         \
  colk[1] = (64 + g * 16) ^ ((fr & 7) << 4);                                    \
  for (int kt = 0; kt < 16; ++kt) {                                             \
    ATYPE_STAGE                                                                 \
    __syncthreads(); /* drains vmcnt+lgkm: tile visible */                      \
    _Pragma("unroll") for (int ks = 0; ks < 2; ++ks) {                          \
      bf16x8 av[4], bv[4];                                                      \
      _Pragma("unroll") for (int m = 0; m < 4; ++m)                             \
        av[m] = *(const bf16x8*)((const char*)Asl + arow + m * 16 * 128 +       \
                                 colk[ks]);                                     \
      _Pragma("unroll") for (int n = 0; n < 4; ++n)                             \
        bv[n] = *(const bf16x8*)((const char*)Bsl + brow + n * 16 * 128 +       \
                                 colk[ks]);                                     \
      _Pragma("unroll") for (int n = 0; n < 4; ++n)                             \
        _Pragma("unroll") for (int m = 0; m < 4; ++m)                           \
          acc[m][n] = mfma_bf16(av[m], bv[n], acc[m][n]);                       \
    }                                                                           \
  }

// QKV GEMM: A = x in f32 (cast fused into reg-staging), B bf16 via gload_lds.
// Grid 1536: xcd=bid&7 -> 8 m-bands; 3 n-chunks of 8.
__global__ __launch_bounds__(256) void gemm_qkv(
    const float* __restrict__ X, const unsigned short* __restrict__ Bt,
    const float* __restrict__ bias,
    unsigned short* __restrict__ Qo, unsigned short* __restrict__ Ko,
    unsigned short* __restrict__ VTo) {
  const int bid = blockIdx.x;
  const int xcd = bid & 7;
  const int local = bid >> 3;          // 0..191
  const int nchunk = local >> 6;       // 0..2
  const int rem = local & 63;
  const int m0 = (xcd * 8 + (rem >> 3)) * 128;
  const int n0 = (nchunk * 8 + (rem & 7)) * 128;
  // A source: f32, pre-swizzled col (bf16-byte col cs -> f32 byte 2*cs)
  const char* fsrc[4];
  const char* bsrc[4];
  {
    const int rr_ = threadIdx.x >> 3;
    const int cs_ = (((threadIdx.x & 7) * 16) ^ ((rr_ & 7) << 4));
#pragma unroll
    for (int c = 0; c < 4; ++c) {
      fsrc[c] = (const char*)X + (size_t)(m0 + c * 32 + rr_) * 4096 + 2 * cs_;
      bsrc[c] = (const char*)Bt + (size_t)(n0 + c * 32 + rr_) * 2048 + cs_;
    }
  }
  GEMM97_BODY(
    /* stage: A f32->bf16 reg path + B gload */
    f32x4 fa[4][2];
    _Pragma("unroll") for (int c = 0; c < 4; ++c) {
      fa[c][0] = *(const f32x4*)(fsrc[c] + kt * 256);
      fa[c][1] = *(const f32x4*)(fsrc[c] + kt * 256 + 16);
    }
    __syncthreads(); /* all waves done reading prev tile */
    _Pragma("unroll") for (int c = 0; c < 4; ++c)
      gload_lds16((const unsigned short*)(bsrc[c] + kt * 128),
                  &Bsl[ldso + c * 2048]);
    _Pragma("unroll") for (int c = 0; c < 4; ++c) {
      alignas(16) unsigned short pk[8];
      _Pragma("unroll") for (int e = 0; e < 4; ++e) pk[e] = f2bf(fa[c][0][e]);
      _Pragma("unroll") for (int e = 0; e < 4; ++e) pk[4 + e] = f2bf(fa[c][1][e]);
      *(uint4*)&Asl[ldso + c * 2048] = *(const uint4*)pk;
    }
  )
#pragma unroll
  for (int i = 0; i < 4; ++i) {
    int mb = m0 + wr * 64 + i * 16 + 4 * g;
    int bidx = mb >> 10;
    int t = mb & 1023;
#pragma unroll
    for (int j = 0; j < 4; ++j) {
      int n = n0 + wc * 64 + j * 16 + fr;
      float bv2 = bias[n];
      int part = n >> 10;
      int nn2 = n & 1023;
      int h = nn2 >> 6, d = nn2 & 63;
      if (part == 2) {
        alignas(8) unsigned short pk[4];
#pragma unroll
        for (int r = 0; r < 4; ++r) pk[r] = f2bf(acc[i][j][r] + bv2);
        *(ushort4*)&VTo[((size_t)(bidx * NHEAD + h) * HDIM + d) * SEQ + t] =
            *(const ushort4*)pk;
      } else {
        unsigned short* dst = (part == 0) ? Qo : Ko;
        float scl = (part == 0) ? 0.125f : 1.0f;   // fold 1/sqrt(hd) into Q
        size_t base = ((size_t)(bidx * NHEAD + h) * SEQ + t) * HDIM + d;
#pragma unroll
        for (int r = 0; r < 4; ++r)
          dst[base + (size_t)r * HDIM] = f2bf((acc[i][j][r] + bv2) * scl);
      }
    }
  }
}

// Proj GEMM: A bf16 (Yb) via gload, B bf16 via gload. Grid 512: xcd -> 8 m-bands x 8 n.
__global__ __launch_bounds__(256) void gemm_proj(
    const unsigned short* __restrict__ A, const unsigned short* __restrict__ Bt,
    const float* __restrict__ bias, float* __restrict__ Out) {
  const int bid = blockIdx.x;
  const int xcd = bid & 7;
  const int local = bid >> 3;          // 0..63
  const int m0 = (xcd * 8 + (local >> 3)) * 128;
  const int n0 = (local & 7) * 128;
  const char* asrc[4];
  const char* bsrc[4];
  {
    const int rr_ = threadIdx.x >> 3;
    const int cs_ = (((threadIdx.x & 7) * 16) ^ ((rr_ & 7) << 4));
#pragma unroll
    for (int c = 0; c < 4; ++c) {
      asrc[c] = (const char*)A + (size_t)(m0 + c * 32 + rr_) * 2048 + cs_;
      bsrc[c] = (const char*)Bt + (size_t)(n0 + c * 32 + rr_) * 2048 + cs_;
    }
  }
  GEMM97_BODY(
    __syncthreads();
    _Pragma("unroll") for (int c = 0; c < 4; ++c)
      gload_lds16((const unsigned short*)(asrc[c] + kt * 128),
                  &Asl[ldso + c * 2048]);
    _Pragma("unroll") for (int c = 0; c < 4; ++c)
      gload_lds16((const unsigned short*)(bsrc[c] + kt * 128),
                  &Bsl[ldso + c * 2048]);
  )
#pragma unroll
  for (int i = 0; i < 4; ++i) {
    int mb = m0 + wr * 64 + i * 16 + 4 * g;
#pragma unroll
    for (int j = 0; j < 4; ++j) {
      int n = n0 + wc * 64 + j * 16 + fr;
      float bv2 = bias[n];
#pragma unroll
      for (int r = 0; r < 4; ++r)
        Out[(size_t)(mb + r) * N_EMBD + n] = acc[i][j][r] + bv2;
    }
  }
}

// ---------------- flash-style causal attention (unchanged from R5) ----------------
__global__ __launch_bounds__(256) void attn_kernel(
    const unsigned short* __restrict__ Q, const unsigned short* __restrict__ Kv,
    const unsigned short* __restrict__ VT, unsigned short* __restrict__ Y) {
  __shared__ unsigned short Kt[2][4096];
  __shared__ unsigned short Vt[2][4096];
  __shared__ unsigned short p_lds[4 * 32 * 72];
  __shared__ float smx[4][32];
  int tid = threadIdx.x, l = tid & 63, w = tid >> 6;
  int orig = blockIdx.x;
  int swz = (orig & 7) * 128 + (orig >> 3);
  int bh = swz >> 3;
  int qi = 7 - (swz & 7);
  int b = bh >> 4, h = bh & 15;
  int q0 = qi * 128;
  int wq = q0 + w * 32;
  const unsigned short* Qb = Q + (size_t)bh * SEQ * HDIM;
  const char* Kc = (const char*)(Kv + (size_t)bh * SEQ * HDIM);
  const char* Vc = (const char*)(VT + (size_t)bh * HDIM * SEQ);
  unsigned short* pw = &p_lds[w * 32 * 72];
  const int g = l >> 4;
  const int fr = l & 15;

  const int P0 = tid * 16, P1 = tid * 16 + 4096;
  const int r0 = P0 >> 7, r1 = P1 >> 7;
  const int s0 = (P0 & 127) ^ ((r0 & 7) << 4);
  const int s1 = (P1 & 127) ^ ((r1 & 7) << 4);
  const char* Kg0 = Kc + r0 * 128 + s0;
  const char* Kg1 = Kc + r1 * 128 + s1;
  const char* Vg0 = Vc + (size_t)r0 * 2048 + s0;
  const char* Vg1 = Vc + (size_t)r1 * 2048 + s1;

  const int bc = (16 * g) ^ ((l & 7) << 4);

  bf16x8 aq[2][2];
#pragma unroll
  for (int i = 0; i < 2; ++i)
#pragma unroll
    for (int ik = 0; ik < 2; ++ik)
      aq[i][ik] = *(const bf16x8*)&Qb[(size_t)(wq + i * 16 + fr) * HDIM + ik * 32 + 8 * g];

  float mrun[2], lpart[2];
  mrun[0] = mrun[1] = -3.0e38f;
  lpart[0] = lpart[1] = 0.0f;
  f32x4 acc_o[2][4];
#pragma unroll
  for (int i = 0; i < 2; ++i)
#pragma unroll
    for (int jd = 0; jd < 4; ++jd)
#pragma unroll
      for (int r = 0; r < 4; ++r) acc_o[i][jd][r] = 0.0f;

  const int n_it = (q0 + 128) >> 6;

  gload_lds16((const unsigned short*)(Kg0), &Kt[0][P0 >> 1]);
  gload_lds16((const unsigned short*)(Kg1), &Kt[0][P1 >> 1]);
  gload_lds16((const unsigned short*)(Vg0), &Vt[0][P0 >> 1]);
  gload_lds16((const unsigned short*)(Vg1), &Vt[0][P1 >> 1]);

  for (int it = 0; it < n_it; ++it) {
    const int kv0 = it << 6;
    const int cur = it & 1;
    if (it + 1 < n_it) {
      const int nx = kv0 + 64;
      gload_lds16((const unsigned short*)(Kg0 + nx * 128), &Kt[cur ^ 1][P0 >> 1]);
      gload_lds16((const unsigned short*)(Kg1 + nx * 128), &Kt[cur ^ 1][P1 >> 1]);
      gload_lds16((const unsigned short*)(Vg0 + nx * 2),   &Vt[cur ^ 1][P0 >> 1]);
      gload_lds16((const unsigned short*)(Vg1 + nx * 2),   &Vt[cur ^ 1][P1 >> 1]);
      asm volatile("s_waitcnt vmcnt(4)" ::: "memory");
    } else {
      asm volatile("s_waitcnt vmcnt(0)" ::: "memory");
    }
    __builtin_amdgcn_sched_barrier(0);
    __builtin_amdgcn_s_barrier();
    __builtin_amdgcn_sched_barrier(0);

    const char* Kbuf = (const char*)Kt[cur];
    const char* Vbuf = (const char*)Vt[cur];

    f32x4 s2[2][4];
#pragma unroll
    for (int i = 0; i < 2; ++i)
#pragma unroll
      for (int j = 0; j < 4; ++j)
#pragma unroll
        for (int r = 0; r < 4; ++r) s2[i][j][r] = 0.0f;

    __builtin_amdgcn_s_setprio(1);
#pragma unroll
    for (int ik = 0; ik < 2; ++ik) {
#pragma unroll
      for (int j = 0; j < 4; ++j) {
        bf16x8 bk = *(const bf16x8*)(Kbuf + (j * 16 + fr) * 128 + (bc ^ (ik << 6)));
#pragma unroll
        for (int i = 0; i < 2; ++i) s2[i][j] = mfma_bf16(bk, aq[i][ik], s2[i][j]);
      }
    }
    __builtin_amdgcn_s_setprio(0);

    bool need_mask = (kv0 + 63) > wq;
    if (need_mask) {
#pragma unroll
      for (int i = 0; i < 2; ++i) {
        int q = wq + i * 16 + fr;
#pragma unroll
        for (int j = 0; j < 4; ++j)
#pragma unroll
          for (int r = 0; r < 4; ++r) {
            int kv = kv0 + j * 16 + 4 * g + r;
            if (kv > q) s2[i][j][r] = -3.0e38f;
          }
      }
    }

    float pm[2];
#pragma unroll
    for (int i = 0; i < 2; ++i) {
      float m01 = fmaxf(fmaxf(s2[i][0][0], s2[i][0][1]), fmaxf(s2[i][0][2], s2[i][0][3]));
      float m11 = fmaxf(fmaxf(s2[i][1][0], s2[i][1][1]), fmaxf(s2[i][1][2], s2[i][1][3]));
      float m21 = fmaxf(fmaxf(s2[i][2][0], s2[i][2][1]), fmaxf(s2[i][2][2], s2[i][2][3]));
      float m31 = fmaxf(fmaxf(s2[i][3][0], s2[i][3][1]), fmaxf(s2[i][3][2], s2[i][3][3]));
      float mm = fmaxf(fmaxf(m01, m11), fmaxf(m21, m31));
      mm = fmaxf(mm, __shfl_xor(mm, 16, 64));
      mm = fmaxf(mm, __shfl_xor(mm, 32, 64));
      pm[i] = mm;
    }

    bool okl = (pm[0] <= mrun[0] + 8.0f) && (pm[1] <= mrun[1] + 8.0f);
    if (!__all(okl)) {
#pragma unroll
      for (int i = 0; i < 2; ++i) {
        float mn = fmaxf(mrun[i], pm[i]);
        float sc = __expf(mrun[i] - mn);
        mrun[i] = mn;
        lpart[i] *= sc;
        if (g == 0) smx[w][i * 16 + fr] = sc;
      }
      asm volatile("s_waitcnt lgkmcnt(0)" ::: "memory");
#pragma unroll
      for (int i = 0; i < 2; ++i)
#pragma unroll
        for (int r = 0; r < 4; ++r) {
          float sc = smx[w][i * 16 + 4 * g + r];
#pragma unroll
          for (int jd = 0; jd < 4; ++jd) acc_o[i][jd][r] *= sc;
        }
    }

#pragma unroll
    for (int i = 0; i < 2; ++i) {
#pragma unroll
      for (int j = 0; j < 4; ++j) {
        float p0 = __expf(s2[i][j][0] - mrun[i]);
        float p1 = __expf(s2[i][j][1] - mrun[i]);
        float p2 = __expf(s2[i][j][2] - mrun[i]);
        float p3 = __expf(s2[i][j][3] - mrun[i]);
        lpart[i] += (p0 + p1) + (p2 + p3);
        ushort4 pk;
        pk.x = f2bf(p0); pk.y = f2bf(p1); pk.z = f2bf(p2); pk.w = f2bf(p3);
        *(ushort4*)&pw[(i * 16 + fr) * 72 + j * 16 + 4 * g] = pk;
      }
    }

    __builtin_amdgcn_s_setprio(1);
#pragma unroll
    for (int ik2 = 0; ik2 < 2; ++ik2) {
      bf16x8 ap[2];
#pragma unroll
      for (int i = 0; i < 2; ++i)
        ap[i] = *(const bf16x8*)&pw[(i * 16 + fr) * 72 + ik2 * 32 + 8 * g];
#pragma unroll
      for (int jd = 0; jd < 4; ++jd) {
        bf16x8 bv = *(const bf16x8*)(Vbuf + (jd * 16 + fr) * 128 + (bc ^ (ik2 << 6)));
#pragma unroll
        for (int i = 0; i < 2; ++i) acc_o[i][jd] = mfma_bf16(ap[i], bv, acc_o[i][jd]);
      }
    }
    __builtin_amdgcn_s_setprio(0);

    asm volatile("s_waitcnt lgkmcnt(0)" ::: "memory");
    __builtin_amdgcn_sched_barrier(0);
    __builtin_amdgcn_s_barrier();
    __builtin_amdgcn_sched_barrier(0);
  }

#pragma unroll
  for (int i = 0; i < 2; ++i) {
    float t = lpart[i];
    t += __shfl_xor(t, 16, 64);
    t += __shfl_xor(t, 32, 64);
    if (g == 0) smx[w][i * 16 + fr] = t;
  }
  asm volatile("s_waitcnt lgkmcnt(0)" ::: "memory");
#pragma unroll
  for (int i = 0; i < 2; ++i)
#pragma unroll
    for (int r = 0; r < 4; ++r) {
      float inv = 1.0f / smx[w][i * 16 + 4 * g + r];
      int q = wq + i * 16 + 4 * g + r;
#pragma unroll
      for (int jd = 0; jd < 4; ++jd)
        Y[((size_t)b * SEQ + q) * N_EMBD + h * HDIM + jd * 16 + fr] =
            f2bf(acc_o[i][jd][r] * inv);
    }
}

// ---------------- launcher ----------------
extern "C" void kernel_launch(void* const* d_in, const int* in_sizes, int n_in,
                              void* d_out, int out_size, void* d_ws, size_t ws_size,
                              hipStream_t stream) {
  (void)in_sizes; (void)n_in; (void)out_size; (void)ws_size;
  const float* x      = (const float*)d_in[0];
  const float* w_attn = (const float*)d_in[1];
  const float* b_attn = (const float*)d_in[2];
  const float* w_proj = (const float*)d_in[3];
  const float* b_proj = (const float*)d_in[4];
  float* out = (float*)d_out;

  char* ws = (char*)d_ws;
  size_t off = 0;
  auto carve = [&](size_t bytes) -> char* {
    char* p = ws + off;
    off += (bytes + 255) & ~(size_t)255;
    return p;
  };
  unsigned short* wTattn = (unsigned short*)carve((size_t)3 * N_EMBD * N_EMBD * 2);
  unsigned short* wTproj = (unsigned short*)carve((size_t)N_EMBD * N_EMBD * 2);
  unsigned short* Qb     = (unsigned short*)carve((size_t)MROWS * N_EMBD * 2);
  unsigned short* Kb     = (unsigned short*)carve((size_t)MROWS * N_EMBD * 2);
  unsigned short* VTb    = (unsigned short*)carve((size_t)MROWS * N_EMBD * 2);
  unsigned short* Yb     = (unsigned short*)carve((size_t)MROWS * N_EMBD * 2);
  carve(4096);

  transpose_cast<<<dim3(3 * N_EMBD / 64, N_EMBD / 64), 256, 0, stream>>>(w_attn, wTattn, N_EMBD, 3 * N_EMBD);
  transpose_cast<<<dim3(N_EMBD / 64, N_EMBD / 64), 256, 0, stream>>>(w_proj, wTproj, N_EMBD, N_EMBD);
  gemm_qkv<<<dim3(1536), 256, 0, stream>>>(x, wTattn, b_attn, Qb, Kb, VTb);
  attn_kernel<<<dim3(BATCH * NHEAD * (SEQ / 128)), 256, 0, stream>>>(Qb, Kb, VTb, Yb);
  gemm_proj<<<dim3(512), 256, 0, stream>>>(Yb, wTproj, b_proj, out);
}

// Round 11
// 176.600 us; speedup vs baseline: 1.0997x; 1.0997x over previous
//
#include <hip/hip_runtime.h>
#include <stdint.h>

#define N_EMBD 1024
#define NHEAD  16
#define HDIM   64
#define BATCH  8
#define SEQ    1024
#define MROWS  (BATCH*SEQ)   // 8192

typedef __bf16 bf16x8 __attribute__((ext_vector_type(8)));
typedef float  f32x4  __attribute__((ext_vector_type(4)));

__device__ inline unsigned short f2bf(float f) {
  uint32_t u = __float_as_uint(f);
  u += 0x7FFFu + ((u >> 16) & 1u);   // RNE; inputs are finite
  return (unsigned short)(u >> 16);
}

__device__ inline f32x4 mfma_bf16(bf16x8 a, bf16x8 b, f32x4 c) {
  return __builtin_amdgcn_mfma_f32_16x16x32_bf16(a, b, c, 0, 0, 0);
}

__device__ inline void gload_lds16(const unsigned short* g, unsigned short* l) {
  __builtin_amdgcn_global_load_lds(
      (const __attribute__((address_space(1))) void*)g,
      (__attribute__((address_space(3))) void*)l,
      16, 0, 0);
}

#define DSB __builtin_amdgcn_sched_barrier(0)
#define BARRIER __builtin_amdgcn_s_barrier()
#define VMC(n) asm volatile("s_waitcnt vmcnt(" #n ")" ::: "memory")
#define LGKM0 asm volatile("s_waitcnt lgkmcnt(0)" ::: "memory"); DSB

// ---------------- cast f32 -> bf16 (vectorized) ----------------
__global__ __launch_bounds__(256) void cast_f32_bf16(
    const float* __restrict__ in, unsigned short* __restrict__ out, int n) {
  int i = (blockIdx.x * 256 + threadIdx.x) * 4;
  if (i >= n) return;
  float4 v = *(const float4*)(in + i);
  ushort4 o;
  o.x = f2bf(v.x); o.y = f2bf(v.y); o.z = f2bf(v.z); o.w = f2bf(v.w);
  *(ushort4*)(out + i) = o;
}

// ---------------- merged transpose+cast for both weights ----------------
// grid.x 0..47: w_attn (N=3072); 48..63: w_proj (N=1024). K=1024 both.
__global__ __launch_bounds__(256) void transpose_cast2(
    const float* __restrict__ wa, unsigned short* __restrict__ oa,
    const float* __restrict__ wp, unsigned short* __restrict__ op) {
  __shared__ unsigned short tile[64 * 72];
  const int K = 1024;
  int bx = blockIdx.x;
  const float* in; unsigned short* out; int N;
  if (bx < 48) { in = wa; out = oa; N = 3072; }
  else         { in = wp; out = op; N = 1024; bx -= 48; }
  int k0 = blockIdx.y * 64, n0 = bx * 64;
  int t = threadIdx.x;
  {
    int col = (t & 15) * 4;
#pragma unroll
    for (int it = 0; it < 4; ++it) {
      int row = (t >> 4) + it * 16;
      float4 v = *(const float4*)(in + (size_t)(k0 + row) * N + n0 + col);
      ushort4 o;
      o.x = f2bf(v.x); o.y = f2bf(v.y); o.z = f2bf(v.z); o.w = f2bf(v.w);
      *(ushort4*)&tile[row * 72 + col] = o;
    }
  }
  __syncthreads();
  {
    int kcol = (t & 7) * 8;
#pragma unroll
    for (int it = 0; it < 2; ++it) {
      int nrow = (t >> 3) + it * 32;
      alignas(16) unsigned short tmp[8];
#pragma unroll
      for (int j = 0; j < 8; ++j) tmp[j] = tile[(kcol + j) * 72 + nrow];
      *(uint4*)(out + (size_t)(n0 + nrow) * K + k0 + kcol) = *(const uint4*)tmp;
    }
  }
}

// ---------------- GEMM v8: R9 structure + double-buffer + counted vmcnt ----------------
// 128x128 tile, BK=64, 4 waves (2x2), per-wave 64x64 = acc[4][4]. LDS 64KB (2 blocks/CU).
// Stage tile kt+2 -> buf[kt&1] at END of iter kt (after lgkm0+barrier frees it);
// VMC(8) at top of iter kt waits only tile kt's 8 loads (issued a full iteration earlier).
// Zero-conflict XOR swizzle via pre-swizzled global source (rule #21), R5-verified.

#define GEMM98_CORE(A_, Bt_, NBN_)                                              \
  __shared__ unsigned short Asl[2][8192];                                       \
  __shared__ unsigned short Bsl[2][8192];                                       \
  const int tid = threadIdx.x;                                                  \
  const int l = tid & 63, w = tid >> 6;                                         \
  const int wr = w >> 1, wc = w & 1;                                            \
  const int g = l >> 4, fr = l & 15;                                            \
  const int nwg = 64 * (NBN_);                                                  \
  int bid = blockIdx.x;                                                         \
  int swzb = (bid & 7) * (nwg >> 3) + (bid >> 3); /* bijective: nwg%8==0 */     \
  const int n0 = (swzb % (NBN_)) * 128;                                         \
  const int m0 = (swzb / (NBN_)) * 128;                                         \
  f32x4 acc[4][4];                                                              \
  _Pragma("unroll") for (int i = 0; i < 4; ++i)                                 \
    _Pragma("unroll") for (int j = 0; j < 4; ++j)                               \
      _Pragma("unroll") for (int r = 0; r < 4; ++r) acc[i][j][r] = 0.0f;        \
  const int rr = tid >> 3;                                                      \
  const int cs = ((tid & 7) * 16) ^ ((rr & 7) << 4);                            \
  const char* srcA[4]; const char* srcB[4];                                     \
  _Pragma("unroll") for (int c = 0; c < 4; ++c) {                               \
    srcA[c] = (const char*)(A_) + (size_t)(m0 + c * 32 + rr) * 2048 + cs;       \
    srcB[c] = (const char*)(Bt_) + (size_t)(n0 + c * 32 + rr) * 2048 + cs;      \
  }                                                                             \
  const int ldso = tid * 8;  /* shorts */                                       \
  const int arow = (wr * 64 + fr) * 128;                                        \
  const int brow = (wc * 64 + fr) * 128;                                        \
  int colk[2];                                                                  \
  colk[0] = (g * 16) ^ ((fr & 7) << 4);                                         \
  colk[1] = (64 + g * 16) ^ ((fr & 7) << 4);                                    \
  /* prologue: tile0 -> buf0, tile1 -> buf1 (issue order matters for vmcnt) */  \
  _Pragma("unroll") for (int c = 0; c < 4; ++c)                                 \
    gload_lds16((const unsigned short*)(srcA[c]), &Asl[0][ldso + c * 2048]);    \
  _Pragma("unroll") for (int c = 0; c < 4; ++c)                                 \
    gload_lds16((const unsigned short*)(srcB[c]), &Bsl[0][ldso + c * 2048]);    \
  _Pragma("unroll") for (int c = 0; c < 4; ++c)                                 \
    gload_lds16((const unsigned short*)(srcA[c] + 128), &Asl[1][ldso + c * 2048]);\
  _Pragma("unroll") for (int c = 0; c < 4; ++c)                                 \
    gload_lds16((const unsigned short*)(srcB[c] + 128), &Bsl[1][ldso + c * 2048]);\
  for (int kt = 0; kt < 16; ++kt) {                                             \
    const int cur = kt & 1;                                                     \
    if (kt < 15) { VMC(8); } else { VMC(0); }                                   \
    DSB; BARRIER; DSB;                                                          \
    _Pragma("unroll") for (int ks = 0; ks < 2; ++ks) {                          \
      bf16x8 av[4], bv[4];                                                      \
      _Pragma("unroll") for (int m = 0; m < 4; ++m)                             \
        av[m] = *(const bf16x8*)((const char*)&Asl[cur][0] + arow +             \
                                 m * 16 * 128 + colk[ks]);                      \
      _Pragma("unroll") for (int n = 0; n < 4; ++n)                             \
        bv[n] = *(const bf16x8*)((const char*)&Bsl[cur][0] + brow +             \
                                 n * 16 * 128 + colk[ks]);                      \
      _Pragma("unroll") for (int n = 0; n < 4; ++n)                             \
        _Pragma("unroll") for (int m = 0; m < 4; ++m)                           \
          acc[m][n] = mfma_bf16(av[m], bv[n], acc[m][n]);                       \
    }                                                                           \
    LGKM0; BARRIER; DSB;  /* all waves' reads of buf cur complete */            \
    if (kt < 14) {                                                              \
      const int ko = (kt + 2) * 128;                                            \
      _Pragma("unroll") for (int c = 0; c < 4; ++c)                             \
        gload_lds16((const unsigned short*)(srcA[c] + ko),                      \
                    &Asl[cur][ldso + c * 2048]);                                \
      _Pragma("unroll") for (int c = 0; c < 4; ++c)                             \
        gload_lds16((const unsigned short*)(srcB[c] + ko),                      \
                    &Bsl[cur][ldso + c * 2048]);                                \
    }                                                                           \
  }

// QKV GEMM: grid 64x24 = 1536 blocks. Scatters Q(1/8)/K [BH][T][64] and VT [BH][64][T].
__global__ __launch_bounds__(256) void gemm_qkv(
    const unsigned short* __restrict__ A, const unsigned short* __restrict__ Bt,
    const float* __restrict__ bias,
    unsigned short* __restrict__ Qo, unsigned short* __restrict__ Ko,
    unsigned short* __restrict__ VTo) {
  GEMM98_CORE(A, Bt, 24)
#pragma unroll
  for (int i = 0; i < 4; ++i) {
    int mb = m0 + wr * 64 + i * 16 + 4 * g;
    int bidx = mb >> 10;
    int t = mb & 1023;
#pragma unroll
    for (int j = 0; j < 4; ++j) {
      int n = n0 + wc * 64 + j * 16 + fr;
      float bv2 = bias[n];
      int part = n >> 10;
      int nn2 = n & 1023;
      int h = nn2 >> 6, d = nn2 & 63;
      if (part == 2) {
        alignas(8) unsigned short pk[4];
#pragma unroll
        for (int r = 0; r < 4; ++r) pk[r] = f2bf(acc[i][j][r] + bv2);
        *(ushort4*)&VTo[((size_t)(bidx * NHEAD + h) * HDIM + d) * SEQ + t] =
            *(const ushort4*)pk;
      } else {
        unsigned short* dst = (part == 0) ? Qo : Ko;
        float scl = (part == 0) ? 0.125f : 1.0f;   // fold 1/sqrt(hd) into Q
        size_t base = ((size_t)(bidx * NHEAD + h) * SEQ + t) * HDIM + d;
#pragma unroll
        for (int r = 0; r < 4; ++r)
          dst[base + (size_t)r * HDIM] = f2bf((acc[i][j][r] + bv2) * scl);
      }
    }
  }
}

// Proj GEMM: grid 64x8 = 512 blocks. f32 out + bias.
__global__ __launch_bounds__(256) void gemm_proj(
    const unsigned short* __restrict__ A, const unsigned short* __restrict__ Bt,
    const float* __restrict__ bias, float* __restrict__ Out) {
  GEMM98_CORE(A, Bt, 8)
#pragma unroll
  for (int i = 0; i < 4; ++i) {
    int mb = m0 + wr * 64 + i * 16 + 4 * g;
#pragma unroll
    for (int j = 0; j < 4; ++j) {
      int n = n0 + wc * 64 + j * 16 + fr;
      float bv2 = bias[n];
#pragma unroll
      for (int r = 0; r < 4; ++r)
        Out[(size_t)(mb + r) * N_EMBD + n] = acc[i][j][r] + bv2;
    }
  }
}

// ---------------- flash-style causal attention (unchanged from R5) ----------------
__global__ __launch_bounds__(256) void attn_kernel(
    const unsigned short* __restrict__ Q, const unsigned short* __restrict__ Kv,
    const unsigned short* __restrict__ VT, unsigned short* __restrict__ Y) {
  __shared__ unsigned short Kt[2][4096];
  __shared__ unsigned short Vt[2][4096];
  __shared__ unsigned short p_lds[4 * 32 * 72];
  __shared__ float smx[4][32];
  int tid = threadIdx.x, l = tid & 63, w = tid >> 6;
  int orig = blockIdx.x;
  int swz = (orig & 7) * 128 + (orig >> 3);
  int bh = swz >> 3;
  int qi = 7 - (swz & 7);
  int b = bh >> 4, h = bh & 15;
  int q0 = qi * 128;
  int wq = q0 + w * 32;
  const unsigned short* Qb = Q + (size_t)bh * SEQ * HDIM;
  const char* Kc = (const char*)(Kv + (size_t)bh * SEQ * HDIM);
  const char* Vc = (const char*)(VT + (size_t)bh * HDIM * SEQ);
  unsigned short* pw = &p_lds[w * 32 * 72];
  const int g = l >> 4;
  const int fr = l & 15;

  const int P0 = tid * 16, P1 = tid * 16 + 4096;
  const int r0 = P0 >> 7, r1 = P1 >> 7;
  const int s0 = (P0 & 127) ^ ((r0 & 7) << 4);
  const int s1 = (P1 & 127) ^ ((r1 & 7) << 4);
  const char* Kg0 = Kc + r0 * 128 + s0;
  const char* Kg1 = Kc + r1 * 128 + s1;
  const char* Vg0 = Vc + (size_t)r0 * 2048 + s0;
  const char* Vg1 = Vc + (size_t)r1 * 2048 + s1;

  const int bc = (16 * g) ^ ((l & 7) << 4);

  bf16x8 aq[2][2];
#pragma unroll
  for (int i = 0; i < 2; ++i)
#pragma unroll
    for (int ik = 0; ik < 2; ++ik)
      aq[i][ik] = *(const bf16x8*)&Qb[(size_t)(wq + i * 16 + fr) * HDIM + ik * 32 + 8 * g];

  float mrun[2], lpart[2];
  mrun[0] = mrun[1] = -3.0e38f;
  lpart[0] = lpart[1] = 0.0f;
  f32x4 acc_o[2][4];
#pragma unroll
  for (int i = 0; i < 2; ++i)
#pragma unroll
    for (int jd = 0; jd < 4; ++jd)
#pragma unroll
      for (int r = 0; r < 4; ++r) acc_o[i][jd][r] = 0.0f;

  const int n_it = (q0 + 128) >> 6;

  gload_lds16((const unsigned short*)(Kg0), &Kt[0][P0 >> 1]);
  gload_lds16((const unsigned short*)(Kg1), &Kt[0][P1 >> 1]);
  gload_lds16((const unsigned short*)(Vg0), &Vt[0][P0 >> 1]);
  gload_lds16((const unsigned short*)(Vg1), &Vt[0][P1 >> 1]);

  for (int it = 0; it < n_it; ++it) {
    const int kv0 = it << 6;
    const int cur = it & 1;
    if (it + 1 < n_it) {
      const int nx = kv0 + 64;
      gload_lds16((const unsigned short*)(Kg0 + nx * 128), &Kt[cur ^ 1][P0 >> 1]);
      gload_lds16((const unsigned short*)(Kg1 + nx * 128), &Kt[cur ^ 1][P1 >> 1]);
      gload_lds16((const unsigned short*)(Vg0 + nx * 2),   &Vt[cur ^ 1][P0 >> 1]);
      gload_lds16((const unsigned short*)(Vg1 + nx * 2),   &Vt[cur ^ 1][P1 >> 1]);
      asm volatile("s_waitcnt vmcnt(4)" ::: "memory");
    } else {
      asm volatile("s_waitcnt vmcnt(0)" ::: "memory");
    }
    __builtin_amdgcn_sched_barrier(0);
    __builtin_amdgcn_s_barrier();
    __builtin_amdgcn_sched_barrier(0);

    const char* Kbuf = (const char*)Kt[cur];
    const char* Vbuf = (const char*)Vt[cur];

    f32x4 s2[2][4];
#pragma unroll
    for (int i = 0; i < 2; ++i)
#pragma unroll
      for (int j = 0; j < 4; ++j)
#pragma unroll
        for (int r = 0; r < 4; ++r) s2[i][j][r] = 0.0f;

    __builtin_amdgcn_s_setprio(1);
#pragma unroll
    for (int ik = 0; ik < 2; ++ik) {
#pragma unroll
      for (int j = 0; j < 4; ++j) {
        bf16x8 bk = *(const bf16x8*)(Kbuf + (j * 16 + fr) * 128 + (bc ^ (ik << 6)));
#pragma unroll
        for (int i = 0; i < 2; ++i) s2[i][j] = mfma_bf16(bk, aq[i][ik], s2[i][j]);
      }
    }
    __builtin_amdgcn_s_setprio(0);

    bool need_mask = (kv0 + 63) > wq;
    if (need_mask) {
#pragma unroll
      for (int i = 0; i < 2; ++i) {
        int q = wq + i * 16 + fr;
#pragma unroll
        for (int j = 0; j < 4; ++j)
#pragma unroll
          for (int r = 0; r < 4; ++r) {
            int kv = kv0 + j * 16 + 4 * g + r;
            if (kv > q) s2[i][j][r] = -3.0e38f;
          }
      }
    }

    float pm[2];
#pragma unroll
    for (int i = 0; i < 2; ++i) {
      float m01 = fmaxf(fmaxf(s2[i][0][0], s2[i][0][1]), fmaxf(s2[i][0][2], s2[i][0][3]));
      float m11 = fmaxf(fmaxf(s2[i][1][0], s2[i][1][1]), fmaxf(s2[i][1][2], s2[i][1][3]));
      float m21 = fmaxf(fmaxf(s2[i][2][0], s2[i][2][1]), fmaxf(s2[i][2][2], s2[i][2][3]));
      float m31 = fmaxf(fmaxf(s2[i][3][0], s2[i][3][1]), fmaxf(s2[i][3][2], s2[i][3][3]));
      float mm = fmaxf(fmaxf(m01, m11), fmaxf(m21, m31));
      mm = fmaxf(mm, __shfl_xor(mm, 16, 64));
      mm = fmaxf(mm, __shfl_xor(mm, 32, 64));
      pm[i] = mm;
    }

    bool okl = (pm[0] <= mrun[0] + 8.0f) && (pm[1] <= mrun[1] + 8.0f);
    if (!__all(okl)) {
#pragma unroll
      for (int i = 0; i < 2; ++i) {
        float mn = fmaxf(mrun[i], pm[i]);
        float sc = __expf(mrun[i] - mn);
        mrun[i] = mn;
        lpart[i] *= sc;
        if (g == 0) smx[w][i * 16 + fr] = sc;
      }
      asm volatile("s_waitcnt lgkmcnt(0)" ::: "memory");
#pragma unroll
      for (int i = 0; i < 2; ++i)
#pragma unroll
        for (int r = 0; r < 4; ++r) {
          float sc = smx[w][i * 16 + 4 * g + r];
#pragma unroll
          for (int jd = 0; jd < 4; ++jd) acc_o[i][jd][r] *= sc;
        }
    }

#pragma unroll
    for (int i = 0; i < 2; ++i) {
#pragma unroll
      for (int j = 0; j < 4; ++j) {
        float p0 = __expf(s2[i][j][0] - mrun[i]);
        float p1 = __expf(s2[i][j][1] - mrun[i]);
        float p2 = __expf(s2[i][j][2] - mrun[i]);
        float p3 = __expf(s2[i][j][3] - mrun[i]);
        lpart[i] += (p0 + p1) + (p2 + p3);
        ushort4 pk;
        pk.x = f2bf(p0); pk.y = f2bf(p1); pk.z = f2bf(p2); pk.w = f2bf(p3);
        *(ushort4*)&pw[(i * 16 + fr) * 72 + j * 16 + 4 * g] = pk;
      }
    }

    __builtin_amdgcn_s_setprio(1);
#pragma unroll
    for (int ik2 = 0; ik2 < 2; ++ik2) {
      bf16x8 ap[2];
#pragma unroll
      for (int i = 0; i < 2; ++i)
        ap[i] = *(const bf16x8*)&pw[(i * 16 + fr) * 72 + ik2 * 32 + 8 * g];
#pragma unroll
      for (int jd = 0; jd < 4; ++jd) {
        bf16x8 bv = *(const bf16x8*)(Vbuf + (jd * 16 + fr) * 128 + (bc ^ (ik2 << 6)));
#pragma unroll
        for (int i = 0; i < 2; ++i) acc_o[i][jd] = mfma_bf16(ap[i], bv, acc_o[i][jd]);
      }
    }
    __builtin_amdgcn_s_setprio(0);

    asm volatile("s_waitcnt lgkmcnt(0)" ::: "memory");
    __builtin_amdgcn_sched_barrier(0);
    __builtin_amdgcn_s_barrier();
    __builtin_amdgcn_sched_barrier(0);
  }

#pragma unroll
  for (int i = 0; i < 2; ++i) {
    float t = lpart[i];
    t += __shfl_xor(t, 16, 64);
    t += __shfl_xor(t, 32, 64);
    if (g == 0) smx[w][i * 16 + fr] = t;
  }
  asm volatile("s_waitcnt lgkmcnt(0)" ::: "memory");
#pragma unroll
  for (int i = 0; i < 2; ++i)
#pragma unroll
    for (int r = 0; r < 4; ++r) {
      float inv = 1.0f / smx[w][i * 16 + 4 * g + r];
      int q = wq + i * 16 + 4 * g + r;
#pragma unroll
      for (int jd = 0; jd < 4; ++jd)
        Y[((size_t)b * SEQ + q) * N_EMBD + h * HDIM + jd * 16 + fr] =
            f2bf(acc_o[i][jd][r] * inv);
    }
}

// ---------------- launcher ----------------
extern "C" void kernel_launch(void* const* d_in, const int* in_sizes, int n_in,
                              void* d_out, int out_size, void* d_ws, size_t ws_size,
                              hipStream_t stream) {
  (void)in_sizes; (void)n_in; (void)out_size; (void)ws_size;
  const float* x      = (const float*)d_in[0];
  const float* w_attn = (const float*)d_in[1];
  const float* b_attn = (const float*)d_in[2];
  const float* w_proj = (const float*)d_in[3];
  const float* b_proj = (const float*)d_in[4];
  float* out = (float*)d_out;

  char* ws = (char*)d_ws;
  size_t off = 0;
  auto carve = [&](size_t bytes) -> char* {
    char* p = ws + off;
    off += (bytes + 255) & ~(size_t)255;
    return p;
  };
  unsigned short* xb     = (unsigned short*)carve((size_t)MROWS * N_EMBD * 2);
  unsigned short* wTattn = (unsigned short*)carve((size_t)3 * N_EMBD * N_EMBD * 2);
  unsigned short* wTproj = (unsigned short*)carve((size_t)N_EMBD * N_EMBD * 2);
  unsigned short* Qb     = (unsigned short*)carve((size_t)MROWS * N_EMBD * 2);
  unsigned short* Kb     = (unsigned short*)carve((size_t)MROWS * N_EMBD * 2);
  unsigned short* VTb    = (unsigned short*)carve((size_t)MROWS * N_EMBD * 2);
  unsigned short* Yb     = (unsigned short*)carve((size_t)MROWS * N_EMBD * 2);
  carve(4096);

  cast_f32_bf16<<<dim3(MROWS * N_EMBD / 1024), 256, 0, stream>>>(x, xb, MROWS * N_EMBD);
  transpose_cast2<<<dim3(64, 16), 256, 0, stream>>>(w_attn, wTattn, w_proj, wTproj);
  gemm_qkv<<<dim3(64 * 24), 256, 0, stream>>>(xb, wTattn, b_attn, Qb, Kb, VTb);
  attn_kernel<<<dim3(BATCH * NHEAD * (SEQ / 128)), 256, 0, stream>>>(Qb, Kb, VTb, Yb);
  gemm_proj<<<dim3(64 * 8), 256, 0, stream>>>(Yb, wTproj, b_proj, out);
}

// Round 12
// 144.544 us; speedup vs baseline: 1.3436x; 1.2218x over previous
//
#include <hip/hip_runtime.h>
#include <stdint.h>

#define N_EMBD 1024
#define NHEAD  16
#define HDIM   64
#define BATCH  8
#define SEQ    1024
#define MROWS  (BATCH*SEQ)   // 8192

typedef __bf16 bf16x8 __attribute__((ext_vector_type(8)));
typedef float  f32x4  __attribute__((ext_vector_type(4)));

__device__ inline unsigned short f2bf(float f) {
  uint32_t u = __float_as_uint(f);
  u += 0x7FFFu + ((u >> 16) & 1u);   // RNE; inputs are finite
  return (unsigned short)(u >> 16);
}

__device__ inline f32x4 mfma_bf16(bf16x8 a, bf16x8 b, f32x4 c) {
  return __builtin_amdgcn_mfma_f32_16x16x32_bf16(a, b, c, 0, 0, 0);
}

__device__ inline void gload_lds16(const unsigned short* g, unsigned short* l) {
  __builtin_amdgcn_global_load_lds(
      (const __attribute__((address_space(1))) void*)g,
      (__attribute__((address_space(3))) void*)l,
      16, 0, 0);
}

#define DSB __builtin_amdgcn_sched_barrier(0)
#define BARRIER __builtin_amdgcn_s_barrier()
#define VMC(n) asm volatile("s_waitcnt vmcnt(" #n ")" ::: "memory")
#define LGKM0 asm volatile("s_waitcnt lgkmcnt(0)" ::: "memory"); DSB

// ---------------- cast f32 -> bf16 (vectorized) ----------------
__global__ __launch_bounds__(256) void cast_f32_bf16(
    const float* __restrict__ in, unsigned short* __restrict__ out, int n) {
  int i = (blockIdx.x * 256 + threadIdx.x) * 4;
  if (i >= n) return;
  float4 v = *(const float4*)(in + i);
  ushort4 o;
  o.x = f2bf(v.x); o.y = f2bf(v.y); o.z = f2bf(v.z); o.w = f2bf(v.w);
  *(ushort4*)(out + i) = o;
}

// ---------------- merged transpose+cast for both weights ----------------
__global__ __launch_bounds__(256) void transpose_cast2(
    const float* __restrict__ wa, unsigned short* __restrict__ oa,
    const float* __restrict__ wp, unsigned short* __restrict__ op) {
  __shared__ unsigned short tile[64 * 72];
  const int K = 1024;
  int bx = blockIdx.x;
  const float* in; unsigned short* out; int N;
  if (bx < 48) { in = wa; out = oa; N = 3072; }
  else         { in = wp; out = op; N = 1024; bx -= 48; }
  int k0 = blockIdx.y * 64, n0 = bx * 64;
  int t = threadIdx.x;
  {
    int col = (t & 15) * 4;
#pragma unroll
    for (int it = 0; it < 4; ++it) {
      int row = (t >> 4) + it * 16;
      float4 v = *(const float4*)(in + (size_t)(k0 + row) * N + n0 + col);
      ushort4 o;
      o.x = f2bf(v.x); o.y = f2bf(v.y); o.z = f2bf(v.z); o.w = f2bf(v.w);
      *(ushort4*)&tile[row * 72 + col] = o;
    }
  }
  __syncthreads();
  {
    int kcol = (t & 7) * 8;
#pragma unroll
    for (int it = 0; it < 2; ++it) {
      int nrow = (t >> 3) + it * 32;
      alignas(16) unsigned short tmp[8];
#pragma unroll
      for (int j = 0; j < 8; ++j) tmp[j] = tile[(kcol + j) * 72 + nrow];
      *(uint4*)(out + (size_t)(n0 + nrow) * K + k0 + kcol) = *(const uint4*)tmp;
    }
  }
}

// ---------------- GEMM v8 (unchanged from R11): dbuf + counted vmcnt ----------------
#define GEMM98_CORE(A_, Bt_, NBN_)                                              \
  __shared__ unsigned short Asl[2][8192];                                       \
  __shared__ unsigned short Bsl[2][8192];                                       \
  const int tid = threadIdx.x;                                                  \
  const int l = tid & 63, w = tid >> 6;                                         \
  const int wr = w >> 1, wc = w & 1;                                            \
  const int g = l >> 4, fr = l & 15;                                            \
  const int nwg = 64 * (NBN_);                                                  \
  int bid = blockIdx.x;                                                         \
  int swzb = (bid & 7) * (nwg >> 3) + (bid >> 3); /* bijective: nwg%8==0 */     \
  const int n0 = (swzb % (NBN_)) * 128;                                         \
  const int m0 = (swzb / (NBN_)) * 128;                                         \
  f32x4 acc[4][4];                                                              \
  _Pragma("unroll") for (int i = 0; i < 4; ++i)                                 \
    _Pragma("unroll") for (int j = 0; j < 4; ++j)                               \
      _Pragma("unroll") for (int r = 0; r < 4; ++r) acc[i][j][r] = 0.0f;        \
  const int rr = tid >> 3;                                                      \
  const int cs = ((tid & 7) * 16) ^ ((rr & 7) << 4);                            \
  const char* srcA[4]; const char* srcB[4];                                     \
  _Pragma("unroll") for (int c = 0; c < 4; ++c) {                               \
    srcA[c] = (const char*)(A_) + (size_t)(m0 + c * 32 + rr) * 2048 + cs;       \
    srcB[c] = (const char*)(Bt_) + (size_t)(n0 + c * 32 + rr) * 2048 + cs;      \
  }                                                                             \
  const int ldso = tid * 8;  /* shorts */                                       \
  const int arow = (wr * 64 + fr) * 128;                                        \
  const int brow = (wc * 64 + fr) * 128;                                        \
  int colk[2];                                                                  \
  colk[0] = (g * 16) ^ ((fr & 7) << 4);                                         \
  colk[1] = (64 + g * 16) ^ ((fr & 7) << 4);                                    \
  _Pragma("unroll") for (int c = 0; c < 4; ++c)                                 \
    gload_lds16((const unsigned short*)(srcA[c]), &Asl[0][ldso + c * 2048]);    \
  _Pragma("unroll") for (int c = 0; c < 4; ++c)                                 \
    gload_lds16((const unsigned short*)(srcB[c]), &Bsl[0][ldso + c * 2048]);    \
  _Pragma("unroll") for (int c = 0; c < 4; ++c)                                 \
    gload_lds16((const unsigned short*)(srcA[c] + 128), &Asl[1][ldso + c * 2048]);\
  _Pragma("unroll") for (int c = 0; c < 4; ++c)                                 \
    gload_lds16((const unsigned short*)(srcB[c] + 128), &Bsl[1][ldso + c * 2048]);\
  for (int kt = 0; kt < 16; ++kt) {                                             \
    const int cur = kt & 1;                                                     \
    if (kt < 15) { VMC(8); } else { VMC(0); }                                   \
    DSB; BARRIER; DSB;                                                          \
    _Pragma("unroll") for (int ks = 0; ks < 2; ++ks) {                          \
      bf16x8 av[4], bv[4];                                                      \
      _Pragma("unroll") for (int m = 0; m < 4; ++m)                             \
        av[m] = *(const bf16x8*)((const char*)&Asl[cur][0] + arow +             \
                                 m * 16 * 128 + colk[ks]);                      \
      _Pragma("unroll") for (int n = 0; n < 4; ++n)                             \
        bv[n] = *(const bf16x8*)((const char*)&Bsl[cur][0] + brow +             \
                                 n * 16 * 128 + colk[ks]);                      \
      _Pragma("unroll") for (int n = 0; n < 4; ++n)                             \
        _Pragma("unroll") for (int m = 0; m < 4; ++m)                           \
          acc[m][n] = mfma_bf16(av[m], bv[n], acc[m][n]);                       \
    }                                                                           \
    LGKM0; BARRIER; DSB;                                                        \
    if (kt < 14) {                                                              \
      const int ko = (kt + 2) * 128;                                            \
      _Pragma("unroll") for (int c = 0; c < 4; ++c)                             \
        gload_lds16((const unsigned short*)(srcA[c] + ko),                      \
                    &Asl[cur][ldso + c * 2048]);                                \
      _Pragma("unroll") for (int c = 0; c < 4; ++c)                             \
        gload_lds16((const unsigned short*)(srcB[c] + ko),                      \
                    &Bsl[cur][ldso + c * 2048]);                                \
    }                                                                           \
  }

__global__ __launch_bounds__(256) void gemm_qkv(
    const unsigned short* __restrict__ A, const unsigned short* __restrict__ Bt,
    const float* __restrict__ bias,
    unsigned short* __restrict__ Qo, unsigned short* __restrict__ Ko,
    unsigned short* __restrict__ VTo) {
  GEMM98_CORE(A, Bt, 24)
#pragma unroll
  for (int i = 0; i < 4; ++i) {
    int mb = m0 + wr * 64 + i * 16 + 4 * g;
    int bidx = mb >> 10;
    int t = mb & 1023;
#pragma unroll
    for (int j = 0; j < 4; ++j) {
      int n = n0 + wc * 64 + j * 16 + fr;
      float bv2 = bias[n];
      int part = n >> 10;
      int nn2 = n & 1023;
      int h = nn2 >> 6, d = nn2 & 63;
      if (part == 2) {
        alignas(8) unsigned short pk[4];
#pragma unroll
        for (int r = 0; r < 4; ++r) pk[r] = f2bf(acc[i][j][r] + bv2);
        *(ushort4*)&VTo[((size_t)(bidx * NHEAD + h) * HDIM + d) * SEQ + t] =
            *(const ushort4*)pk;
      } else {
        unsigned short* dst = (part == 0) ? Qo : Ko;
        float scl = (part == 0) ? 0.125f : 1.0f;   // fold 1/sqrt(hd) into Q
        size_t base = ((size_t)(bidx * NHEAD + h) * SEQ + t) * HDIM + d;
#pragma unroll
        for (int r = 0; r < 4; ++r)
          dst[base + (size_t)r * HDIM] = f2bf((acc[i][j][r] + bv2) * scl);
      }
    }
  }
}

__global__ __launch_bounds__(256) void gemm_proj(
    const unsigned short* __restrict__ A, const unsigned short* __restrict__ Bt,
    const float* __restrict__ bias, float* __restrict__ Out) {
  GEMM98_CORE(A, Bt, 8)
#pragma unroll
  for (int i = 0; i < 4; ++i) {
    int mb = m0 + wr * 64 + i * 16 + 4 * g;
#pragma unroll
    for (int j = 0; j < 4; ++j) {
      int n = n0 + wc * 64 + j * 16 + fr;
      float bv2 = bias[n];
#pragma unroll
      for (int r = 0; r < 4; ++r)
        Out[(size_t)(mb + r) * N_EMBD + n] = acc[i][j][r] + bv2;
    }
  }
}

// ---------------- flash attention v2: balanced pairs, shfl-free defer, cvt_pk pack ----
// Block handles q-tiles {pairIdx, 7-pairIdx} (18 kv-iters each block, uniform).
// Grid 512 = 2 blocks/CU exactly. mrun init 0; per-iter defer check is in-lane only
// (15 fmax + __all); full shfl-reduce+rescale only in the (rare) exceed branch.
__global__ __launch_bounds__(256) void attn_kernel(
    const unsigned short* __restrict__ Q, const unsigned short* __restrict__ Kv,
    const unsigned short* __restrict__ VT, unsigned short* __restrict__ Y) {
  __shared__ unsigned short Kt[2][4096];
  __shared__ unsigned short Vt[2][4096];
  __shared__ unsigned short p_lds[4 * 32 * 72];
  __shared__ float smx[4][32];
  int tid = threadIdx.x, l = tid & 63, w = tid >> 6;
  int bid = blockIdx.x;
  int swz = (bid & 7) * 64 + (bid >> 3);   // bijective (512 % 8 == 0)
  int bh = swz >> 2;
  int pairIdx = swz & 3;
  int b = bh >> 4, h = bh & 15;
  const unsigned short* Qb = Q + (size_t)bh * SEQ * HDIM;
  const char* Kc = (const char*)(Kv + (size_t)bh * SEQ * HDIM);
  const char* Vc = (const char*)(VT + (size_t)bh * HDIM * SEQ);
  unsigned short* pw = &p_lds[w * 32 * 72];
  const int g = l >> 4;
  const int fr = l & 15;

  const int P0 = tid * 16, P1 = tid * 16 + 4096;
  const int r0 = P0 >> 7, r1 = P1 >> 7;
  const int s0 = (P0 & 127) ^ ((r0 & 7) << 4);
  const int s1 = (P1 & 127) ^ ((r1 & 7) << 4);
  const char* Kg0 = Kc + r0 * 128 + s0;
  const char* Kg1 = Kc + r1 * 128 + s1;
  const char* Vg0 = Vc + (size_t)r0 * 2048 + s0;
  const char* Vg1 = Vc + (size_t)r1 * 2048 + s1;

  const int bc = (16 * g) ^ ((l & 7) << 4);

  for (int part = 0; part < 2; ++part) {
    const int qt = (part == 0) ? pairIdx : 7 - pairIdx;   // light first (L2 prefix)
    const int q0 = qt * 128;
    const int wq = q0 + w * 32;

    bf16x8 aq[2][2];
#pragma unroll
    for (int i = 0; i < 2; ++i)
#pragma unroll
      for (int ik = 0; ik < 2; ++ik)
        aq[i][ik] = *(const bf16x8*)&Qb[(size_t)(wq + i * 16 + fr) * HDIM + ik * 32 + 8 * g];

    float mrun[2], lpart[2];
    mrun[0] = mrun[1] = 0.0f;      // valid: rescale path handles any exceedance
    lpart[0] = lpart[1] = 0.0f;
    f32x4 acc_o[2][4];
#pragma unroll
    for (int i = 0; i < 2; ++i)
#pragma unroll
      for (int jd = 0; jd < 4; ++jd)
#pragma unroll
        for (int r = 0; r < 4; ++r) acc_o[i][jd][r] = 0.0f;

    const int n_it = (q0 + 128) >> 6;

    // prologue: stage tile 0
    gload_lds16((const unsigned short*)(Kg0), &Kt[0][P0 >> 1]);
    gload_lds16((const unsigned short*)(Kg1), &Kt[0][P1 >> 1]);
    gload_lds16((const unsigned short*)(Vg0), &Vt[0][P0 >> 1]);
    gload_lds16((const unsigned short*)(Vg1), &Vt[0][P1 >> 1]);

    for (int it = 0; it < n_it; ++it) {
      const int kv0 = it << 6;
      const int cur = it & 1;
      if (it + 1 < n_it) {
        const int nx = kv0 + 64;
        gload_lds16((const unsigned short*)(Kg0 + nx * 128), &Kt[cur ^ 1][P0 >> 1]);
        gload_lds16((const unsigned short*)(Kg1 + nx * 128), &Kt[cur ^ 1][P1 >> 1]);
        gload_lds16((const unsigned short*)(Vg0 + nx * 2),   &Vt[cur ^ 1][P0 >> 1]);
        gload_lds16((const unsigned short*)(Vg1 + nx * 2),   &Vt[cur ^ 1][P1 >> 1]);
        VMC(4);
      } else {
        VMC(0);
      }
      DSB; BARRIER; DSB;

      const char* Kbuf = (const char*)Kt[cur];
      const char* Vbuf = (const char*)Vt[cur];

      f32x4 s2[2][4];
#pragma unroll
      for (int i = 0; i < 2; ++i)
#pragma unroll
        for (int j = 0; j < 4; ++j)
#pragma unroll
          for (int r = 0; r < 4; ++r) s2[i][j][r] = 0.0f;

      __builtin_amdgcn_s_setprio(1);
#pragma unroll
      for (int ik = 0; ik < 2; ++ik) {
#pragma unroll
        for (int j = 0; j < 4; ++j) {
          bf16x8 bk = *(const bf16x8*)(Kbuf + (j * 16 + fr) * 128 + (bc ^ (ik << 6)));
#pragma unroll
          for (int i = 0; i < 2; ++i) s2[i][j] = mfma_bf16(bk, aq[i][ik], s2[i][j]);
        }
      }
      __builtin_amdgcn_s_setprio(0);

      bool need_mask = (kv0 + 63) > wq;
      if (need_mask) {
#pragma unroll
        for (int i = 0; i < 2; ++i) {
          int q = wq + i * 16 + fr;
#pragma unroll
          for (int j = 0; j < 4; ++j)
#pragma unroll
            for (int r = 0; r < 4; ++r) {
              int kv = kv0 + j * 16 + 4 * g + r;
              if (kv > q) s2[i][j][r] = -3.0e38f;
            }
        }
      }

      // per-lane defer check: in-lane max only (no shfl on the common path)
      float pmloc[2];
#pragma unroll
      for (int i = 0; i < 2; ++i) {
        float m01 = fmaxf(fmaxf(s2[i][0][0], s2[i][0][1]), fmaxf(s2[i][0][2], s2[i][0][3]));
        float m11 = fmaxf(fmaxf(s2[i][1][0], s2[i][1][1]), fmaxf(s2[i][1][2], s2[i][1][3]));
        float m21 = fmaxf(fmaxf(s2[i][2][0], s2[i][2][1]), fmaxf(s2[i][2][2], s2[i][2][3]));
        float m31 = fmaxf(fmaxf(s2[i][3][0], s2[i][3][1]), fmaxf(s2[i][3][2], s2[i][3][3]));
        pmloc[i] = fmaxf(fmaxf(m01, m11), fmaxf(m21, m31));
      }
      bool ok = (pmloc[0] <= mrun[0] + 8.0f) && (pmloc[1] <= mrun[1] + 8.0f);
      if (!__all(ok)) {   // rare: full reduce + rescale
#pragma unroll
        for (int i = 0; i < 2; ++i) {
          float mm = pmloc[i];
          mm = fmaxf(mm, __shfl_xor(mm, 16, 64));
          mm = fmaxf(mm, __shfl_xor(mm, 32, 64));
          float mn = fmaxf(mrun[i], mm);
          float sc = __expf(mrun[i] - mn);
          mrun[i] = mn;
          lpart[i] *= sc;
          if (g == 0) smx[w][i * 16 + fr] = sc;
        }
        asm volatile("s_waitcnt lgkmcnt(0)" ::: "memory");
#pragma unroll
        for (int i = 0; i < 2; ++i)
#pragma unroll
          for (int r = 0; r < 4; ++r) {
            float sc = smx[w][i * 16 + 4 * g + r];
#pragma unroll
            for (int jd = 0; jd < 4; ++jd) acc_o[i][jd][r] *= sc;
          }
      }

      // P = exp(S - m); per-lane partial sums; cvt_pk pack + b64 writes
#pragma unroll
      for (int i = 0; i < 2; ++i) {
#pragma unroll
        for (int j = 0; j < 4; ++j) {
          float p0 = __expf(s2[i][j][0] - mrun[i]);
          float p1 = __expf(s2[i][j][1] - mrun[i]);
          float p2 = __expf(s2[i][j][2] - mrun[i]);
          float p3 = __expf(s2[i][j][3] - mrun[i]);
          lpart[i] += (p0 + p1) + (p2 + p3);
          uint2 pk2;
          asm("v_cvt_pk_bf16_f32 %0, %1, %2" : "=v"(pk2.x) : "v"(p0), "v"(p1));
          asm("v_cvt_pk_bf16_f32 %0, %1, %2" : "=v"(pk2.y) : "v"(p2), "v"(p3));
          *(uint2*)&pw[(i * 16 + fr) * 72 + j * 16 + 4 * g] = pk2;
        }
      }

      __builtin_amdgcn_s_setprio(1);
#pragma unroll
      for (int ik2 = 0; ik2 < 2; ++ik2) {
        bf16x8 ap[2];
#pragma unroll
        for (int i = 0; i < 2; ++i)
          ap[i] = *(const bf16x8*)&pw[(i * 16 + fr) * 72 + ik2 * 32 + 8 * g];
#pragma unroll
        for (int jd = 0; jd < 4; ++jd) {
          bf16x8 bv = *(const bf16x8*)(Vbuf + (jd * 16 + fr) * 128 + (bc ^ (ik2 << 6)));
#pragma unroll
          for (int i = 0; i < 2; ++i) acc_o[i][jd] = mfma_bf16(ap[i], bv, acc_o[i][jd]);
        }
      }
      __builtin_amdgcn_s_setprio(0);

      asm volatile("s_waitcnt lgkmcnt(0)" ::: "memory");
      DSB; BARRIER; DSB;
    }

    // finalize row sums: 2 shfl + LDS broadcast, write Y
#pragma unroll
    for (int i = 0; i < 2; ++i) {
      float t = lpart[i];
      t += __shfl_xor(t, 16, 64);
      t += __shfl_xor(t, 32, 64);
      if (g == 0) smx[w][i * 16 + fr] = t;
    }
    asm volatile("s_waitcnt lgkmcnt(0)" ::: "memory");
#pragma unroll
    for (int i = 0; i < 2; ++i)
#pragma unroll
      for (int r = 0; r < 4; ++r) {
        float inv = 1.0f / smx[w][i * 16 + 4 * g + r];
        int q = wq + i * 16 + 4 * g + r;
#pragma unroll
        for (int jd = 0; jd < 4; ++jd)
          Y[((size_t)b * SEQ + q) * N_EMBD + h * HDIM + jd * 16 + fr] =
              f2bf(acc_o[i][jd][r] * inv);
      }
  }
}

// ---------------- launcher ----------------
extern "C" void kernel_launch(void* const* d_in, const int* in_sizes, int n_in,
                              void* d_out, int out_size, void* d_ws, size_t ws_size,
                              hipStream_t stream) {
  (void)in_sizes; (void)n_in; (void)out_size; (void)ws_size;
  const float* x      = (const float*)d_in[0];
  const float* w_attn = (const float*)d_in[1];
  const float* b_attn = (const float*)d_in[2];
  const float* w_proj = (const float*)d_in[3];
  const float* b_proj = (const float*)d_in[4];
  float* out = (float*)d_out;

  char* ws = (char*)d_ws;
  size_t off = 0;
  auto carve = [&](size_t bytes) -> char* {
    char* p = ws + off;
    off += (bytes + 255) & ~(size_t)255;
    return p;
  };
  unsigned short* xb     = (unsigned short*)carve((size_t)MROWS * N_EMBD * 2);
  unsigned short* wTattn = (unsigned short*)carve((size_t)3 * N_EMBD * N_EMBD * 2);
  unsigned short* wTproj = (unsigned short*)carve((size_t)N_EMBD * N_EMBD * 2);
  unsigned short* Qb     = (unsigned short*)carve((size_t)MROWS * N_EMBD * 2);
  unsigned short* Kb     = (unsigned short*)carve((size_t)MROWS * N_EMBD * 2);
  unsigned short* VTb    = (unsigned short*)carve((size_t)MROWS * N_EMBD * 2);
  unsigned short* Yb     = (unsigned short*)carve((size_t)MROWS * N_EMBD * 2);
  carve(4096);

  cast_f32_bf16<<<dim3(MROWS * N_EMBD / 1024), 256, 0, stream>>>(x, xb, MROWS * N_EMBD);
  transpose_cast2<<<dim3(64, 16), 256, 0, stream>>>(w_attn, wTattn, w_proj, wTproj);
  gemm_qkv<<<dim3(64 * 24), 256, 0, stream>>>(xb, wTattn, b_attn, Qb, Kb, VTb);
  attn_kernel<<<dim3(512), 256, 0, stream>>>(Qb, Kb, VTb, Yb);
  gemm_proj<<<dim3(64 * 8), 256, 0, stream>>>(Yb, wTproj, b_proj, out);
}